// Round 1
// baseline (85.603 us; speedup 1.0000x reference)
//
#include <hip/hip_runtime.h>
#include <math.h>

#define BB 8
#define NN 256
#define XHIN 9
#define XHHID 64
#define POSHID 192
#define RPB 4   // rows per block in out_kernel: 512 blocks, 2/CU, fma:load 4:1

// ---------------------------------------------------------------------------
// K1: per-batch masked mean removal. One block per batch.
// Writes centered x SoA (ws_xc[(b*3+c)*NN+n]) and mask count (ws_cnt[b]).
// ---------------------------------------------------------------------------
__global__ __launch_bounds__(256) void mean_kernel(
    const float* __restrict__ xh, const float* __restrict__ mask,
    float* __restrict__ ws_xc, float* __restrict__ ws_cnt)
{
  const int b = blockIdx.x;
  const int n = threadIdx.x;

  const float* p = xh + (b * NN + n) * XHIN;
  const float x0 = p[0], x1 = p[1], x2 = p[2];
  const float m = mask[b * NN + n];

  float a0 = x0 * m, a1 = x1 * m, a2 = x2 * m, a3 = m;
  #pragma unroll
  for (int off = 32; off > 0; off >>= 1) {
    a0 += __shfl_down(a0, off, 64);
    a1 += __shfl_down(a1, off, 64);
    a2 += __shfl_down(a2, off, 64);
    a3 += __shfl_down(a3, off, 64);
  }
  __shared__ float red[4][4];
  const int lane = n & 63, wv = n >> 6;
  if (lane == 0) { red[wv][0] = a0; red[wv][1] = a1; red[wv][2] = a2; red[wv][3] = a3; }
  __syncthreads();

  const float s0 = red[0][0] + red[1][0] + red[2][0] + red[3][0];
  const float s1 = red[0][1] + red[1][1] + red[2][1] + red[3][1];
  const float s2 = red[0][2] + red[1][2] + red[2][2] + red[3][2];
  const float cnt = red[0][3] + red[1][3] + red[2][3] + red[3][3];
  const float inv = 1.0f / cnt;

  ws_xc[(b * 3 + 0) * NN + n] = (x0 - s0 * inv) * m;
  ws_xc[(b * 3 + 1) * NN + n] = (x1 - s1 * inv) * m;
  ws_xc[(b * 3 + 2) * NN + n] = (x2 - s2 * inv) * m;
  if (n == 0) ws_cnt[b] = cnt;
}

// ---------------------------------------------------------------------------
// K2: S-field. One block per (b,i) row — 2048 blocks keeps 8 waves/SIMD so
// the quarter-rate trans pipe (v_sin/v_cos) stays saturated.
//   ws_S[(b*256+i)*128 + f] = (mi/cnt) * sum_j m_j * sin/cos(2*pi*d_ij*freq_f)
// (sin in f=[0,64), cos in [64,128)); already scaled by mi/cnt.
// ---------------------------------------------------------------------------
__global__ __launch_bounds__(256) void sfield_kernel(
    const float* __restrict__ ws_xc, const float* __restrict__ ws_cnt,
    const float* __restrict__ mask, float* __restrict__ ws_S)
{
  const int blk = blockIdx.x;
  const int b = blk >> 8;
  const int i = blk & 255;
  const int tid = threadIdx.x;

  __shared__ float2 dm_s[NN];                    // (dist, mask_j)
  __shared__ float part[4][128];

  // phase 1: distances for all j (coalesced SoA reads)
  const float* xcb = ws_xc + b * 3 * NN;
  const float xi0 = xcb[0 * NN + i];
  const float xi1 = xcb[1 * NN + i];
  const float xi2 = xcb[2 * NN + i];
  {
    const int j = tid;
    const float dx = xi0 - xcb[0 * NN + j];
    const float dy = xi1 - xcb[1 * NN + j];
    const float dz = xi2 - xcb[2 * NN + j];
    const float sq = fmaf(dx, dx, fmaf(dy, dy, dz * dz));
    dm_s[j] = make_float2(sqrtf(sq + 1e-12f), mask[b * NN + j]);
  }
  __syncthreads();

  // phase 2: thread (jg,f): accumulate sin/cos for freq f over 64 j's
  const int f = tid & 63, jg = tid >> 6;
  // freq = 100^(f/64) = exp2(f * log2(100)/64)
  const float freq = __builtin_exp2f((float)f * 0.10381025296523007f);
  float ss = 0.f, cc = 0.f;
  const float2* dmp = dm_s + jg * 64;
  #pragma unroll 16
  for (int u = 0; u < 64; ++u) {
    const float2 dm = dmp[u];                    // one b64 broadcast / iter
    const float rv = __builtin_amdgcn_fractf(dm.x * freq);  // revolutions
    ss = fmaf(__builtin_amdgcn_sinf(rv), dm.y, ss);
    cc = fmaf(__builtin_amdgcn_cosf(rv), dm.y, cc);
  }
  part[jg][f] = ss;
  part[jg][64 + f] = cc;
  __syncthreads();

  if (tid < 128) {
    const float cnt = ws_cnt[b];
    const float mi = dm_s[i].y;
    ws_S[(size_t)blk * 128 + tid] =
        (part[0][tid] + part[1][tid] + part[2][tid] + part[3][tid]) * (mi / cnt);
  }
}

// ---------------------------------------------------------------------------
// K3: output kernel. One block per 4 output rows (same batch; 256/RPB divides
// evenly so tiles never straddle b). 256 threads:
//   tid <  192 : col=tid, 4 pe outputs:  acc[r] = S_row[r] . Wp[:,col] + bias
//   tid >= 192 : oo=tid-192, 4 xh-embed outputs via LDS-staged Wxh
// Wp is read ONCE per 4 rows (4x less L2 traffic than per-row blocks) with
// coalesced lanes; S rows come from LDS via uniform-address b128 broadcasts.
// ---------------------------------------------------------------------------
__global__ __launch_bounds__(256) void out_kernel(
    const float* __restrict__ ws_S, const float* __restrict__ ws_xc,
    const float* __restrict__ ws_cnt, const float* __restrict__ mask,
    const float* __restrict__ xh,
    const float* __restrict__ Wxh, const float* __restrict__ bxh,
    const float* __restrict__ Wp, const float* __restrict__ bp,
    float* __restrict__ out)
{
  const int blk = blockIdx.x;
  const int row0 = blk * RPB;                    // global row = b*256+i
  const int b = row0 >> 8;
  const int i0 = row0 & 255;
  const int tid = threadIdx.x;

  __shared__ __align__(16) float S_l[RPB][128];  // scaled S rows
  __shared__ float ins_l[RPB][XHIN];             // [xc(3), h(6)] per row
  __shared__ float Wxh_l[XHIN * XHHID];          // 576 floats
  __shared__ float bxh_l[XHHID];
  __shared__ float bscale_l[RPB];                // mi*256/cnt (pe bias scale)
  __shared__ float mi_l[RPB];                    // mask_i

  // stage S: RPB*128 = 512 floats, 128 threads x float4, coalesced
  if (tid < 128)
    ((float4*)S_l)[tid] = ((const float4*)(ws_S + (size_t)row0 * 128))[tid];
  // stage Wxh (576 floats)
  if (tid < 192) {
    Wxh_l[tid]       = Wxh[tid];
    Wxh_l[tid + 192] = Wxh[tid + 192];
    Wxh_l[tid + 384] = Wxh[tid + 384];
  }
  if (tid < XHHID) bxh_l[tid] = bxh[tid];
  if (tid < RPB * XHIN) {                        // 36 threads: embed inputs
    const int r = tid / XHIN, k = tid % XHIN;
    const int i = i0 + r;
    ins_l[r][k] = (k < 3) ? ws_xc[(b * 3 + k) * NN + i]
                          : xh[(size_t)(b * NN + i) * XHIN + k];
  }
  if (tid < RPB) {
    const float m = mask[b * NN + i0 + tid];
    mi_l[tid] = m;
    bscale_l[tid] = m * 256.0f / ws_cnt[b];
  }
  __syncthreads();

  if (tid < POSHID) {
    const int col = tid;
    float acc[RPB];
    #pragma unroll
    for (int r = 0; r < RPB; ++r) acc[r] = bp[col] * bscale_l[r];

    #pragma unroll 8
    for (int k4 = 0; k4 < 32; ++k4) {
      const float* w = Wp + (k4 * 4) * POSHID + col;      // lanes coalesced
      const float w0 = w[0 * POSHID];
      const float w1 = w[1 * POSHID];
      const float w2 = w[2 * POSHID];
      const float w3 = w[3 * POSHID];
      #pragma unroll
      for (int r = 0; r < RPB; ++r) {
        const float4 s = ((const float4*)S_l[r])[k4];     // b128 broadcast
        acc[r] = fmaf(s.w, w3, fmaf(s.z, w2, fmaf(s.y, w1, fmaf(s.x, w0, acc[r]))));
      }
    }
    #pragma unroll
    for (int r = 0; r < RPB; ++r)
      out[(size_t)(row0 + r) * 256 + 64 + col] = acc[r];
  } else {
    const int oo = tid - POSHID;                 // 0..63
    #pragma unroll
    for (int r = 0; r < RPB; ++r) {
      float acc = bxh_l[oo];
      #pragma unroll
      for (int k = 0; k < XHIN; ++k)
        acc = fmaf(ins_l[r][k], Wxh_l[k * XHHID + oo], acc);
      out[(size_t)(row0 + r) * 256 + oo] = acc * mi_l[r];
    }
  }
}

extern "C" void kernel_launch(void* const* d_in, const int* in_sizes, int n_in,
                              void* d_out, int out_size, void* d_ws, size_t ws_size,
                              hipStream_t stream) {
  // setup_inputs order: t, xh, node_mask, edge_mask, W_xh, b_xh, W_pos, b_pos
  const float* xh   = (const float*)d_in[1];
  const float* mask = (const float*)d_in[2];
  const float* Wxh  = (const float*)d_in[4];
  const float* bxh  = (const float*)d_in[5];
  const float* Wp   = (const float*)d_in[6];
  const float* bp   = (const float*)d_in[7];
  float* out = (float*)d_out;

  float* ws_xc  = (float*)d_ws;            // BB*3*NN floats (SoA centered x)
  float* ws_cnt = ws_xc + BB * 3 * NN;     // BB floats (mask counts)
  float* ws_S   = ws_cnt + 64;             // pad to 16B align; 2048*128 floats

  mean_kernel<<<BB, 256, 0, stream>>>(xh, mask, ws_xc, ws_cnt);
  sfield_kernel<<<BB * NN, 256, 0, stream>>>(ws_xc, ws_cnt, mask, ws_S);
  out_kernel<<<BB * NN / RPB, 256, 0, stream>>>(ws_S, ws_xc, ws_cnt, mask, xh,
                                                Wxh, bxh, Wp, bp, out);
}

// Round 2
// 80.947 us; speedup vs baseline: 1.0575x; 1.0575x over previous
//
#include <hip/hip_runtime.h>
#include <math.h>

#define BB 8
#define NN 256
#define XHIN 9
#define XHHID 64
#define POSHID 192

// ---------------------------------------------------------------------------
// K1: per-batch masked mean removal. One block per batch.
// Writes centered x SoA (ws_xc[(b*3+c)*NN+n]) and mask count (ws_cnt[b]).
// ---------------------------------------------------------------------------
__global__ __launch_bounds__(256) void mean_kernel(
    const float* __restrict__ xh, const float* __restrict__ mask,
    float* __restrict__ ws_xc, float* __restrict__ ws_cnt)
{
  const int b = blockIdx.x;
  const int n = threadIdx.x;

  const float* p = xh + (b * NN + n) * XHIN;
  const float x0 = p[0], x1 = p[1], x2 = p[2];
  const float m = mask[b * NN + n];

  float a0 = x0 * m, a1 = x1 * m, a2 = x2 * m, a3 = m;
  #pragma unroll
  for (int off = 32; off > 0; off >>= 1) {
    a0 += __shfl_down(a0, off, 64);
    a1 += __shfl_down(a1, off, 64);
    a2 += __shfl_down(a2, off, 64);
    a3 += __shfl_down(a3, off, 64);
  }
  __shared__ float red[4][4];
  const int lane = n & 63, wv = n >> 6;
  if (lane == 0) { red[wv][0] = a0; red[wv][1] = a1; red[wv][2] = a2; red[wv][3] = a3; }
  __syncthreads();

  const float s0 = red[0][0] + red[1][0] + red[2][0] + red[3][0];
  const float s1 = red[0][1] + red[1][1] + red[2][1] + red[3][1];
  const float s2 = red[0][2] + red[1][2] + red[2][2] + red[3][2];
  const float cnt = red[0][3] + red[1][3] + red[2][3] + red[3][3];
  const float inv = 1.0f / cnt;

  ws_xc[(b * 3 + 0) * NN + n] = (x0 - s0 * inv) * m;
  ws_xc[(b * 3 + 1) * NN + n] = (x1 - s1 * inv) * m;
  ws_xc[(b * 3 + 2) * NN + n] = (x2 - s2 * inv) * m;
  if (n == 0) ws_cnt[b] = cnt;
}

// ---------------------------------------------------------------------------
// K2 (re-fused): one block per (b,i) row, does everything.
// Phase 2 restructure vs R0: thread = (jg in [0,8), fp in [0,32)) handles
// TWO frequencies (2fp, 2fp+1) over 32 j's -> ds_read_b64 count halved
// (LDS pipe is per-CU, shared by all 4 SIMDs), loop overhead halved,
// trans-op count identical. part is now [8][128].
// ---------------------------------------------------------------------------
__global__ __launch_bounds__(256) void pe_kernel(
    const float* __restrict__ ws_xc, const float* __restrict__ ws_cnt,
    const float* __restrict__ mask, const float* __restrict__ xh,
    const float* __restrict__ Wxh, const float* __restrict__ bxh,
    const float* __restrict__ Wp, const float* __restrict__ bp,
    float* __restrict__ out)
{
  const int blk = blockIdx.x;
  const int b = blk >> 8;
  const int i = blk & 255;
  const int tid = threadIdx.x;

  __shared__ float2 dm_s[NN];                    // (dist, mask_j)
  __shared__ __align__(16) float part[8][128];   // [jg][sin 0..63 | cos 64..127]
  __shared__ __align__(16) float Ssc[128];
  __shared__ float ins_s[XHIN];                  // [xc_i(3), h_i(6)]

  // phase 1: distances for all j (coalesced SoA reads)
  const float* xcb = ws_xc + b * 3 * NN;
  const float xi0 = xcb[0 * NN + i];
  const float xi1 = xcb[1 * NN + i];
  const float xi2 = xcb[2 * NN + i];
  {
    const int j = tid;
    const float dx = xi0 - xcb[0 * NN + j];
    const float dy = xi1 - xcb[1 * NN + j];
    const float dz = xi2 - xcb[2 * NN + j];
    const float sq = fmaf(dx, dx, fmaf(dy, dy, dz * dz));
    dm_s[j] = make_float2(sqrtf(sq + 1e-12f), mask[b * NN + j]);
  }
  if (tid < XHIN)
    ins_s[tid] = (tid < 3) ? xcb[tid * NN + i] : xh[(b * NN + i) * XHIN + tid];
  __syncthreads();

  // phase 2: two freqs per thread over 32 j's.
  const int fp = tid & 31, jg = tid >> 5;
  // freq_f = 100^(f/64) = exp2(f * log2(100)/64); same formula as R0 (bit-match)
  const float f0 = (float)(2 * fp);
  const float freq0 = __builtin_exp2f(f0 * 0.10381025296523007f);
  const float freq1 = __builtin_exp2f((f0 + 1.0f) * 0.10381025296523007f);
  float ss0 = 0.f, cc0 = 0.f, ss1 = 0.f, cc1 = 0.f;
  const float2* dmp = dm_s + jg * 32;
  #pragma unroll 8
  for (int u = 0; u < 32; ++u) {
    const float2 dm = dmp[u];                    // one b64 broadcast / 2 cells
    const float r0 = __builtin_amdgcn_fractf(dm.x * freq0);  // revolutions
    const float r1 = __builtin_amdgcn_fractf(dm.x * freq1);
    ss0 = fmaf(__builtin_amdgcn_sinf(r0), dm.y, ss0);
    cc0 = fmaf(__builtin_amdgcn_cosf(r0), dm.y, cc0);
    ss1 = fmaf(__builtin_amdgcn_sinf(r1), dm.y, ss1);
    cc1 = fmaf(__builtin_amdgcn_cosf(r1), dm.y, cc1);
  }
  *(float2*)&part[jg][2 * fp]      = make_float2(ss0, ss1);
  *(float2*)&part[jg][64 + 2 * fp] = make_float2(cc0, cc1);
  __syncthreads();

  const float cnt = ws_cnt[b];
  const float mi = dm_s[i].y;                    // mask_i, already staged
  if (tid < 128) {
    float s = part[0][tid];
    #pragma unroll
    for (int g = 1; g < 8; ++g) s += part[g][tid];
    Ssc[tid] = s * (mi / cnt);
  }
  __syncthreads();

  if (tid < POSHID) {
    // phase 3a: 192 pe outputs, 128-MAC dot; Ssc via b128 broadcasts
    const float4* S4 = (const float4*)Ssc;
    float acc = bp[tid] * (mi * 256.0f / cnt);
    #pragma unroll 8
    for (int k4 = 0; k4 < 32; ++k4) {
      const float4 s = S4[k4];
      const float* w = Wp + (k4 * 4) * POSHID + tid;
      acc = fmaf(s.x, w[0 * POSHID], acc);
      acc = fmaf(s.y, w[1 * POSHID], acc);
      acc = fmaf(s.z, w[2 * POSHID], acc);
      acc = fmaf(s.w, w[3 * POSHID], acc);
    }
    out[(size_t)(b * NN + i) * 256 + 64 + tid] = acc;
  } else {
    // phase 3b (concurrent): 64 xh-embedding outputs for this node
    const int oo = tid - POSHID;                 // 0..63
    float acc = bxh[oo];
    #pragma unroll
    for (int k = 0; k < XHIN; ++k)
      acc = fmaf(ins_s[k], Wxh[k * XHHID + oo], acc);
    out[(size_t)(b * NN + i) * 256 + oo] = acc * mi;
  }
}

extern "C" void kernel_launch(void* const* d_in, const int* in_sizes, int n_in,
                              void* d_out, int out_size, void* d_ws, size_t ws_size,
                              hipStream_t stream) {
  // setup_inputs order: t, xh, node_mask, edge_mask, W_xh, b_xh, W_pos, b_pos
  const float* xh   = (const float*)d_in[1];
  const float* mask = (const float*)d_in[2];
  const float* Wxh  = (const float*)d_in[4];
  const float* bxh  = (const float*)d_in[5];
  const float* Wp   = (const float*)d_in[6];
  const float* bp   = (const float*)d_in[7];
  float* out = (float*)d_out;

  float* ws_xc  = (float*)d_ws;           // BB*3*NN floats (SoA centered x)
  float* ws_cnt = ws_xc + BB * 3 * NN;    // BB floats (mask counts)

  mean_kernel<<<BB, 256, 0, stream>>>(xh, mask, ws_xc, ws_cnt);
  pe_kernel<<<BB * NN, 256, 0, stream>>>(ws_xc, ws_cnt, mask, xh, Wxh, bxh, Wp, bp, out);
}